// Round 12
// baseline (786.689 us; speedup 1.0000x reference)
//
#include <hip/hip_runtime.h>
#include <hip/hip_bf16.h>
#include <math.h>

#define Hdim 1024
#define Vdim 50257
#define Bdim 64
#define Tdim 2048

#define TCH 64
#define NCHUNK (Tdim / TCH)  // 32
#define PSTRIDE (Hdim + 4)
#define NWOB 786             // ceil(50257/64) Wo blocks (64 cols each)
#define NSB 2048             // scores blocks (64 batch x 32 chunks)
#define PLS 3144             // lsm partials per row = NWOB*4 waves
#define REPW 5               // instrumentation: repeat k_wo2 body (idempotent)

typedef short bf16x8 __attribute__((ext_vector_type(8)));
typedef float f32x4 __attribute__((ext_vector_type(4)));

__device__ __forceinline__ unsigned short f2bf(float f) {
  unsigned int u = __float_as_uint(f);
  unsigned int r = u + 0x7FFFu + ((u >> 16) & 1u);  // RNE
  return (unsigned short)(r >> 16);
}

// guarded online-softmax merge: never produces NaN when either side empty
__device__ __forceinline__ void mlmerge(float& m, float& l, float mo, float lo) {
  float M = fmaxf(m, mo);
  float a = (l == 0.f) ? 0.f : l * __expf(m - M);
  float c = (lo == 0.f) ? 0.f : lo * __expf(mo - M);
  m = M;
  l = a + c;
}

// ---------------- fused GRU GEMM (both ih and hh jobs in one launch) --------
template <bool FUSED>
__global__ __launch_bounds__(256) void k_gru_gemm(
    const int* __restrict__ idx, const float* __restrict__ Ai,
    const float* __restrict__ ctx, const float* __restrict__ Ah,
    const float* __restrict__ Wi, const float* __restrict__ Wh,
    float* __restrict__ gi_part, float* __restrict__ gh_part, int nSplitI,
    int kLen) {
  __shared__ float As[16][68];
  __shared__ float Ws[16][68];
  int tid = threadIdx.x;
  bool isI = (int)blockIdx.y < nSplitI;
  int split = isI ? blockIdx.y : (blockIdx.y - nSplitI);
  const float* W = isI ? Wi : Wh;
  int ldw = (FUSED && isI) ? 2048 : 1024;
  int kBase = split * kLen;
  int nIter = kLen >> 4;
  int tx = tid & 15, ty = tid >> 4;
  int n0 = blockIdx.x * 64;

  int am = tid >> 2, akk = (tid & 3) << 2;
  int wn = tid >> 2, wkk = (tid & 3) << 2;

  float acc[4][4];
#pragma unroll
  for (int i = 0; i < 4; i++)
#pragma unroll
    for (int j = 0; j < 4; j++) acc[i][j] = 0.f;

  float4 aReg, wReg;
  auto loadTile = [&](int k0) {
    int kg = k0 + akk;
    const float* asrc;
    if (isI) {
      if (FUSED)
        asrc = (kg < 1024) ? (Ai + (long)idx[am] * 1024 + kg)
                           : (ctx + (long)am * 1024 + (kg - 1024));
      else
        asrc = Ai + (long)am * 1024 + kg;
    } else {
      asrc = Ah + (long)am * 1024 + kg;
    }
    aReg = *(const float4*)asrc;
    wReg = *(const float4*)(W + (long)(n0 + wn) * ldw + k0 + wkk);
  };

  loadTile(kBase);
  for (int it = 0; it < nIter; ++it) {
    if (it) __syncthreads();
    As[akk + 0][am] = aReg.x; As[akk + 1][am] = aReg.y;
    As[akk + 2][am] = aReg.z; As[akk + 3][am] = aReg.w;
    Ws[wkk + 0][wn] = wReg.x; Ws[wkk + 1][wn] = wReg.y;
    Ws[wkk + 2][wn] = wReg.z; Ws[wkk + 3][wn] = wReg.w;
    __syncthreads();
    if (it + 1 < nIter) loadTile(kBase + (it + 1) * 16);
#pragma unroll
    for (int k = 0; k < 16; ++k) {
      float4 a = *(const float4*)&As[k][ty << 2];
      float4 w = *(const float4*)&Ws[k][tx << 2];
      acc[0][0] += a.x * w.x; acc[0][1] += a.x * w.y; acc[0][2] += a.x * w.z; acc[0][3] += a.x * w.w;
      acc[1][0] += a.y * w.x; acc[1][1] += a.y * w.y; acc[1][2] += a.y * w.z; acc[1][3] += a.y * w.w;
      acc[2][0] += a.z * w.x; acc[2][1] += a.z * w.y; acc[2][2] += a.z * w.z; acc[2][3] += a.z * w.w;
      acc[3][0] += a.w * w.x; acc[3][1] += a.w * w.y; acc[3][2] += a.w * w.z; acc[3][3] += a.w * w.w;
    }
  }
  float* C = (isI ? gi_part : gh_part) + (long)split * 64 * 3072;
#pragma unroll
  for (int i = 0; i < 4; i++) {
    int m = (ty << 2) + i;
#pragma unroll
    for (int j = 0; j < 4; j++) {
      int n = n0 + (tx << 2) + j;
      C[(long)m * 3072 + n] = acc[i][j];
    }
  }
}

// ---------------- GRU gate + split-K combine + fused outputs ----------------
__global__ void k_gate(const float* __restrict__ gi_part, int ski,
                       const float* __restrict__ gh_part, int skh,
                       const float* __restrict__ b_ih, const float* __restrict__ b_hh,
                       const float* __restrict__ hprev,
                       const int* __restrict__ idx, const float* __restrict__ E,
                       float* __restrict__ hout, float* __restrict__ out1_layer,
                       unsigned short* __restrict__ catb) {
  int i = blockIdx.x * blockDim.x + threadIdx.x;
  if (i >= Bdim * Hdim) return;
  int b = i >> 10, h = i & 1023;
  float ir = b_ih[h], iz = b_ih[Hdim + h], in = b_ih[2 * Hdim + h];
  float hr = b_hh[h], hz = b_hh[Hdim + h], hn = b_hh[2 * Hdim + h];
  for (int s = 0; s < ski; ++s) {
    const float* g = gi_part + ((long)s * 64 + b) * 3072;
    ir += g[h]; iz += g[Hdim + h]; in += g[2 * Hdim + h];
  }
  for (int s = 0; s < skh; ++s) {
    const float* g = gh_part + ((long)s * 64 + b) * 3072;
    hr += g[h]; hz += g[Hdim + h]; hn += g[2 * Hdim + h];
  }
  float r = 1.f / (1.f + __expf(-(ir + hr)));
  float z = 1.f / (1.f + __expf(-(iz + hz)));
  float n = tanhf(in + r * hn);
  float hv = (1.f - z) * n + z * hprev[i];
  hout[i] = hv;
  out1_layer[i] = hv + E[(long)idx[b] * 1024 + h];
  if (catb) catb[(long)b * 2048 + h] = f2bf(hv);
}

// ---------------- q = h1 @ Wa (TRANSW), split-K 8x128, reg-prefetch ---------
__global__ __launch_bounds__(256) void k_qgemm(const float* __restrict__ A,
                                               const float* __restrict__ W,
                                               float* __restrict__ Cpart) {
  __shared__ float As[16][68];
  __shared__ float Ws[16][68];
  int tid = threadIdx.x;
  int tx = tid & 15, ty = tid >> 4;
  int n0 = blockIdx.x * 64;
  int kBase = blockIdx.y * 128;
  int am = tid >> 2, akk = (tid & 3) << 2;
  int wkk = tid >> 4, wn4 = (tid & 15) << 2;

  float acc[4][4];
#pragma unroll
  for (int i = 0; i < 4; i++)
#pragma unroll
    for (int j = 0; j < 4; j++) acc[i][j] = 0.f;

  float4 aReg, wReg;
  auto loadTile = [&](int k0) {
    aReg = *(const float4*)(A + (long)am * 1024 + k0 + akk);
    wReg = *(const float4*)(W + (long)(k0 + wkk) * 1024 + n0 + wn4);
  };

  loadTile(kBase);
  for (int it = 0; it < 8; ++it) {
    if (it) __syncthreads();
    As[akk + 0][am] = aReg.x; As[akk + 1][am] = aReg.y;
    As[akk + 2][am] = aReg.z; As[akk + 3][am] = aReg.w;
    *(float4*)&Ws[wkk][wn4] = wReg;
    __syncthreads();
    if (it + 1 < 8) loadTile(kBase + (it + 1) * 16);
#pragma unroll
    for (int k = 0; k < 16; ++k) {
      float4 a = *(const float4*)&As[k][ty << 2];
      float4 w = *(const float4*)&Ws[k][tx << 2];
      acc[0][0] += a.x * w.x; acc[0][1] += a.x * w.y; acc[0][2] += a.x * w.z; acc[0][3] += a.x * w.w;
      acc[1][0] += a.y * w.x; acc[1][1] += a.y * w.y; acc[1][2] += a.y * w.z; acc[1][3] += a.y * w.w;
      acc[2][0] += a.z * w.x; acc[2][1] += a.z * w.y; acc[2][2] += a.z * w.z; acc[2][3] += a.z * w.w;
      acc[3][0] += a.w * w.x; acc[3][1] += a.w * w.y; acc[3][2] += a.w * w.z; acc[3][3] += a.w * w.w;
    }
  }
  float* C = Cpart + (long)blockIdx.y * 65536;
#pragma unroll
  for (int i = 0; i < 4; i++) {
    int m = (ty << 2) + i;
#pragma unroll
    for (int j = 0; j < 4; j++) {
      int n = n0 + (tx << 2) + j;
      C[(long)m * 1024 + n] = acc[i][j];
    }
  }
}

// ---------------- fused: Wo half-1 ∥ scores+partial-ctx (pipelined) ---------
__global__ __launch_bounds__(256) void k_fused2(
    const float* __restrict__ enc, const float* __restrict__ q_part,
    float* __restrict__ scores, float* __restrict__ part,
    const unsigned short* __restrict__ catb, const float* __restrict__ Wo,
    float* __restrict__ pl) {
  __shared__ float s_acc[4][Hdim];
  __shared__ float s_ml[4][2];
  int tid = threadIdx.x, w = tid >> 6, lane = tid & 63;

  if (blockIdx.x < NWOB) {
    // ---------- Wo GEMM, K in [0,1024) (h1 half of catb): partial logits ----
    int wb = blockIdx.x;
    int n = wb * 64 + w * 16 + (lane & 15);
    bool valid = n < Vdim;
    const float* wrow = Wo + (long)(valid ? n : 0) * (2 * Hdim);
    int kb = (lane >> 4) * 8;
    int r16 = lane & 15;
    const unsigned short* ar0 = catb + (long)(r16) * 2048 + kb;
    const unsigned short* ar1 = catb + (long)(16 + r16) * 2048 + kb;
    const unsigned short* ar2 = catb + (long)(32 + r16) * 2048 + kb;
    const unsigned short* ar3 = catb + (long)(48 + r16) * 2048 + kb;
    f32x4 acc0 = {0.f, 0.f, 0.f, 0.f}, acc1 = acc0, acc2 = acc0, acc3 = acc0;
#pragma unroll 2
    for (int k0 = 0; k0 < 1024; k0 += 32) {
      float4 w0 = *(const float4*)(wrow + k0 + kb);
      float4 w1 = *(const float4*)(wrow + k0 + kb + 4);
      bf16x8 bf;
      bf[0] = (short)f2bf(w0.x); bf[1] = (short)f2bf(w0.y);
      bf[2] = (short)f2bf(w0.z); bf[3] = (short)f2bf(w0.w);
      bf[4] = (short)f2bf(w1.x); bf[5] = (short)f2bf(w1.y);
      bf[6] = (short)f2bf(w1.z); bf[7] = (short)f2bf(w1.w);
      bf16x8 a0 = *(const bf16x8*)(ar0 + k0);
      bf16x8 a1 = *(const bf16x8*)(ar1 + k0);
      bf16x8 a2 = *(const bf16x8*)(ar2 + k0);
      bf16x8 a3 = *(const bf16x8*)(ar3 + k0);
      acc0 = __builtin_amdgcn_mfma_f32_16x16x32_bf16(a0, bf, acc0, 0, 0, 0);
      acc1 = __builtin_amdgcn_mfma_f32_16x16x32_bf16(a1, bf, acc1, 0, 0, 0);
      acc2 = __builtin_amdgcn_mfma_f32_16x16x32_bf16(a2, bf, acc2, 0, 0, 0);
      acc3 = __builtin_amdgcn_mfma_f32_16x16x32_bf16(a3, bf, acc3, 0, 0, 0);
    }
    if (valid) {
      int rbase = (lane >> 4) * 4;
#pragma unroll
      for (int r = 0; r < 4; ++r) {
        pl[(long)(0 * 16 + rbase + r) * Vdim + n] = acc0[r];
        pl[(long)(1 * 16 + rbase + r) * Vdim + n] = acc1[r];
        pl[(long)(2 * 16 + rbase + r) * Vdim + n] = acc2[r];
        pl[(long)(3 * 16 + rbase + r) * Vdim + n] = acc3[r];
      }
    }
    return;
  }

  // ---------- scores + online-softmax partial context (pipelined loads) ----
  int sb = blockIdx.x - NWOB;
  int b = sb >> 5, ch = sb & 31;
  auto qsum = [&](int p) {
    float4 r = make_float4(0.f, 0.f, 0.f, 0.f);
#pragma unroll
    for (int s = 0; s < 8; ++s) {
      float4 v = *(const float4*)(q_part + (long)s * 65536 + b * 1024 + p * 4);
      r.x += v.x; r.y += v.y; r.z += v.z; r.w += v.w;
    }
    return r;
  };
  float4 q0 = qsum(lane), q1 = qsum(lane + 64), q2 = qsum(lane + 128), q3 = qsum(lane + 192);
  int tbase = ch * TCH + w * 16;

  float m = -INFINITY, l = 0.f;
  float4 a0 = make_float4(0, 0, 0, 0), a1 = a0, a2 = a0, a3 = a0;
  const float4* e4 = (const float4*)(enc + ((long)tbase * Bdim + b) * Hdim);
  const float4* f4 = (const float4*)(enc + ((long)(tbase + 1) * Bdim + b) * Hdim);
  float4 eA0 = e4[lane], eA1 = e4[lane + 64], eA2 = e4[lane + 128], eA3 = e4[lane + 192];
  float4 fA0 = f4[lane], fA1 = f4[lane + 64], fA2 = f4[lane + 128], fA3 = f4[lane + 192];
#pragma unroll
  for (int i = 0; i < 16; i += 2) {
    float4 eB0, eB1, eB2, eB3, fB0, fB1, fB2, fB3;
    if (i + 2 < 16) {
      const float4* g4 = (const float4*)(enc + ((long)(tbase + i + 2) * Bdim + b) * Hdim);
      const float4* h4 = (const float4*)(enc + ((long)(tbase + i + 3) * Bdim + b) * Hdim);
      eB0 = g4[lane]; eB1 = g4[lane + 64]; eB2 = g4[lane + 128]; eB3 = g4[lane + 192];
      fB0 = h4[lane]; fB1 = h4[lane + 64]; fB2 = h4[lane + 128]; fB3 = h4[lane + 192];
    }
    float p = q0.x * eA0.x + q0.y * eA0.y + q0.z * eA0.z + q0.w * eA0.w
            + q1.x * eA1.x + q1.y * eA1.y + q1.z * eA1.z + q1.w * eA1.w
            + q2.x * eA2.x + q2.y * eA2.y + q2.z * eA2.z + q2.w * eA2.w
            + q3.x * eA3.x + q3.y * eA3.y + q3.z * eA3.z + q3.w * eA3.w;
    float p2 = q0.x * fA0.x + q0.y * fA0.y + q0.z * fA0.z + q0.w * fA0.w
             + q1.x * fA1.x + q1.y * fA1.y + q1.z * fA1.z + q1.w * fA1.w
             + q2.x * fA2.x + q2.y * fA2.y + q2.z * fA2.z + q2.w * fA2.w
             + q3.x * fA3.x + q3.y * fA3.y + q3.z * fA3.z + q3.w * fA3.w;
#pragma unroll
    for (int off = 1; off < 64; off <<= 1) {
      p += __shfl_xor(p, off, 64);
      p2 += __shfl_xor(p2, off, 64);
    }
    if (lane == 0) {
      scores[(long)b * Tdim + tbase + i] = p;
      scores[(long)b * Tdim + tbase + i + 1] = p2;
    }
    // defer-max: rescale only when the pair-max beats m by >8 (wave-uniform)
    float pm = fmaxf(p, p2);
    if (pm > m + 8.f) {
      float sc = __expf(m - pm);  // exp(-inf)=0 on first pair
      l *= sc;
      a0.x *= sc; a0.y *= sc; a0.z *= sc; a0.w *= sc;
      a1.x *= sc; a1.y *= sc; a1.z *= sc; a1.w *= sc;
      a2.x *= sc; a2.y *= sc; a2.z *= sc; a2.w *= sc;
      a3.x *= sc; a3.y *= sc; a3.z *= sc; a3.w *= sc;
      m = pm;
    }
    float w1 = __expf(p - m);   // bounded by e^8
    float w2 = __expf(p2 - m);
    l += w1 + w2;
    a0.x += w1 * eA0.x + w2 * fA0.x; a0.y += w1 * eA0.y + w2 * fA0.y;
    a0.z += w1 * eA0.z + w2 * fA0.z; a0.w += w1 * eA0.w + w2 * fA0.w;
    a1.x += w1 * eA1.x + w2 * fA1.x; a1.y += w1 * eA1.y + w2 * fA1.y;
    a1.z += w1 * eA1.z + w2 * fA1.z; a1.w += w1 * eA1.w + w2 * fA1.w;
    a2.x += w1 * eA2.x + w2 * fA2.x; a2.y += w1 * eA2.y + w2 * fA2.y;
    a2.z += w1 * eA2.z + w2 * fA2.z; a2.w += w1 * eA2.w + w2 * fA2.w;
    a3.x += w1 * eA3.x + w2 * fA3.x; a3.y += w1 * eA3.y + w2 * fA3.y;
    a3.z += w1 * eA3.z + w2 * fA3.z; a3.w += w1 * eA3.w + w2 * fA3.w;
    eA0 = eB0; eA1 = eB1; eA2 = eB2; eA3 = eB3;
    fA0 = fB0; fA1 = fB1; fA2 = fB2; fA3 = fB3;
  }
  float4* sa = (float4*)s_acc[w];
  sa[lane] = a0; sa[lane + 64] = a1; sa[lane + 128] = a2; sa[lane + 192] = a3;
  if (lane == 0) { s_ml[w][0] = m; s_ml[w][1] = l; }
  __syncthreads();
  float M = fmaxf(fmaxf(s_ml[0][0], s_ml[1][0]), fmaxf(s_ml[2][0], s_ml[3][0]));
  float L = 0.f;
  float4 o = make_float4(0, 0, 0, 0);
  for (int ww = 0; ww < 4; ++ww) {
    float wgt = __expf(s_ml[ww][0] - M);
    L += wgt * s_ml[ww][1];
    float4 v = ((const float4*)s_acc[ww])[tid];
    o.x += wgt * v.x; o.y += wgt * v.y; o.z += wgt * v.z; o.w += wgt * v.w;
  }
  float* pp = part + ((long)b * NCHUNK + ch) * PSTRIDE;
  ((float4*)pp)[tid] = o;
  if (tid == 0) { pp[Hdim] = M; pp[Hdim + 1] = L; }
}

// ---------------- combine partials -> context + catb + attn output ----------
__global__ void k_ctx_combine(const float* __restrict__ part,
                              const float* __restrict__ scores,
                              float* __restrict__ ctx_out,
                              unsigned short* __restrict__ catb,
                              float* __restrict__ attn_out) {
  int b = blockIdx.x, tid = threadIdx.x;  // 256
  __shared__ float ms[NCHUNK], ls[NCHUNK];
  if (tid < NCHUNK) {
    const float* pp = part + ((long)b * NCHUNK + tid) * PSTRIDE;
    ms[tid] = pp[Hdim];
    ls[tid] = pp[Hdim + 1];
  }
  __syncthreads();
  float m = -INFINITY;
  for (int c = 0; c < NCHUNK; ++c) m = fmaxf(m, ms[c]);
  float l = 0.f;
  for (int c = 0; c < NCHUNK; ++c) l += __expf(ms[c] - m) * ls[c];
  float4 a = make_float4(0, 0, 0, 0);
  for (int c = 0; c < NCHUNK; ++c) {
    float w = __expf(ms[c] - m);
    float4 v = ((const float4*)(part + ((long)b * NCHUNK + c) * PSTRIDE))[tid];
    a.x += w * v.x; a.y += w * v.y; a.z += w * v.z; a.w += w * v.w;
  }
  float inv = 1.f / l;
  a.x *= inv; a.y *= inv; a.z *= inv; a.w *= inv;
  ((float4*)(ctx_out + (long)b * Hdim))[tid] = a;
  ushort4 ob;
  ob.x = f2bf(a.x); ob.y = f2bf(a.y); ob.z = f2bf(a.z); ob.w = f2bf(a.w);
  *(ushort4*)(catb + (long)b * 2 * Hdim + Hdim + tid * 4) = ob;
  const float* srow = scores + (long)b * Tdim;
  float* arow = attn_out + (long)b * Tdim;
  for (int t = tid; t < Tdim; t += 256) arow[t] = __expf(srow[t] - m) * inv;
}

// ---------------- Wo half-2 + bias + tanh + lsm partials (REPW-instrumented)
__global__ __launch_bounds__(256) void k_wo2(const unsigned short* __restrict__ catb,
                                             const float* __restrict__ Wo,
                                             const float* __restrict__ bo,
                                             const float* __restrict__ pl,
                                             float* __restrict__ out,
                                             float2* __restrict__ plsm) {
  int tid = threadIdx.x, w = tid >> 6, lane = tid & 63;
  int wb = blockIdx.x;
  int n = wb * 64 + w * 16 + (lane & 15);
  bool valid = n < Vdim;
  const float* wrow = Wo + (long)(valid ? n : 0) * (2 * Hdim);
  int kb = (lane >> 4) * 8;
  int r16 = lane & 15;
  int rbase = (lane >> 4) * 4;
  const unsigned short* ar0 = catb + (long)(r16) * 2048 + kb;
  const unsigned short* ar1 = catb + (long)(16 + r16) * 2048 + kb;
  const unsigned short* ar2 = catb + (long)(32 + r16) * 2048 + kb;
  const unsigned short* ar3 = catb + (long)(48 + r16) * 2048 + kb;
  for (int rep = 0; rep < REPW; ++rep) {
    f32x4 acc0 = {0.f, 0.f, 0.f, 0.f}, acc1 = acc0, acc2 = acc0, acc3 = acc0;
    if (valid) {
#pragma unroll
      for (int r = 0; r < 4; ++r) {
        acc0[r] = pl[(long)(0 * 16 + rbase + r) * Vdim + n];
        acc1[r] = pl[(long)(1 * 16 + rbase + r) * Vdim + n];
        acc2[r] = pl[(long)(2 * 16 + rbase + r) * Vdim + n];
        acc3[r] = pl[(long)(3 * 16 + rbase + r) * Vdim + n];
      }
    }
#pragma unroll 2
    for (int k0 = 1024; k0 < 2048; k0 += 32) {
      float4 w0 = *(const float4*)(wrow + k0 + kb);
      float4 w1 = *(const float4*)(wrow + k0 + kb + 4);
      bf16x8 bf;
      bf[0] = (short)f2bf(w0.x); bf[1] = (short)f2bf(w0.y);
      bf[2] = (short)f2bf(w0.z); bf[3] = (short)f2bf(w0.w);
      bf[4] = (short)f2bf(w1.x); bf[5] = (short)f2bf(w1.y);
      bf[6] = (short)f2bf(w1.z); bf[7] = (short)f2bf(w1.w);
      bf16x8 a0 = *(const bf16x8*)(ar0 + k0);
      bf16x8 a1 = *(const bf16x8*)(ar1 + k0);
      bf16x8 a2 = *(const bf16x8*)(ar2 + k0);
      bf16x8 a3 = *(const bf16x8*)(ar3 + k0);
      acc0 = __builtin_amdgcn_mfma_f32_16x16x32_bf16(a0, bf, acc0, 0, 0, 0);
      acc1 = __builtin_amdgcn_mfma_f32_16x16x32_bf16(a1, bf, acc1, 0, 0, 0);
      acc2 = __builtin_amdgcn_mfma_f32_16x16x32_bf16(a2, bf, acc2, 0, 0, 0);
      acc3 = __builtin_amdgcn_mfma_f32_16x16x32_bf16(a3, bf, acc3, 0, 0, 0);
    }
    float bias = valid ? bo[n] : 0.f;
    int widx = wb * 4 + w;
#define LSMG(G, ACCG)                                                          \
    {                                                                          \
      _Pragma("unroll") for (int r = 0; r < 4; ++r) {                          \
        float tv = tanhf(ACCG[r] + bias);                                      \
        if (valid) out[(long)(G * 16 + rbase + r) * Vdim + n] = tv;            \
        float mm = valid ? tv : -INFINITY;                                     \
        float ll = valid ? 1.f : 0.f;                                          \
        _Pragma("unroll") for (int msk = 1; msk < 16; msk <<= 1) {             \
          float mo = __shfl_xor(mm, msk, 64);                                  \
          float lo = __shfl_xor(ll, msk, 64);                                  \
          mlmerge(mm, ll, mo, lo);                                             \
        }                                                                      \
        if ((lane & 15) == 0)                                                  \
          plsm[(long)(G * 16 + rbase + r) * PLS + widx] = make_float2(mm, ll); \
      }                                                                        \
    }
    LSMG(0, acc0)
    LSMG(1, acc1)
    LSMG(2, acc2)
    LSMG(3, acc3)
#undef LSMG
  }
}

// ---------------- final log_softmax: reduce plsm + subtract ----------------
__global__ __launch_bounds__(256) void k_lsm_final(float* __restrict__ out,
                                                   const float2* __restrict__ plsm) {
  int b = blockIdx.x, c = blockIdx.y;
  int tid = threadIdx.x, w = tid >> 6, lane = tid & 63;
  float m = -INFINITY, l = 0.f;
  for (int i = tid; i < PLS; i += 256) {
    float2 p = plsm[(long)b * PLS + i];
    mlmerge(m, l, p.x, p.y);
  }
#pragma unroll
  for (int msk = 1; msk < 64; msk <<= 1) {
    float mo = __shfl_xor(m, msk, 64);
    float lo = __shfl_xor(l, msk, 64);
    mlmerge(m, l, mo, lo);
  }
  __shared__ float sm[4], sl[4];
  if (lane == 0) { sm[w] = m; sl[w] = l; }
  __syncthreads();
  float M = -INFINITY, L = 0.f;
#pragma unroll
  for (int i = 0; i < 4; ++i) mlmerge(M, L, sm[i], sl[i]);
  float lg = M + logf(L);
  const int seg = (Vdim + 3) / 4;
  int v0 = c * seg, v1 = min(v0 + seg, Vdim);
  float* row = out + (long)b * Vdim;
  for (int v = v0 + tid; v < v1; v += 256) row[v] -= lg;
}

extern "C" void kernel_launch(void* const* d_in, const int* in_sizes, int n_in,
                              void* d_out, int out_size, void* d_ws, size_t ws_size,
                              hipStream_t stream) {
  const int* inputs   = (const int*)d_in[0];
  const float* hidden = (const float*)d_in[1];
  const float* context= (const float*)d_in[2];
  const float* enc    = (const float*)d_in[3];
  const float* E      = (const float*)d_in[4];
  const float* W_ih0  = (const float*)d_in[5];
  const float* W_hh0  = (const float*)d_in[6];
  const float* b_ih0  = (const float*)d_in[7];
  const float* b_hh0  = (const float*)d_in[8];
  const float* W_ih1  = (const float*)d_in[9];
  const float* W_hh1  = (const float*)d_in[10];
  const float* b_ih1  = (const float*)d_in[11];
  const float* b_hh1  = (const float*)d_in[12];
  const float* Wa     = (const float*)d_in[13];
  // d_in[14] = ba: dropped — constant per-row score shift is softmax-invariant
  const float* Wo     = (const float*)d_in[15];
  const float* bo     = (const float*)d_in[16];

  float* ws = (float*)d_ws;
  float* gi_part = ws;                         // 16*64*3072 = 3145728
  float* gh_part = gi_part + 3145728;          // 8*64*3072 = 1572864
  float* h0      = gh_part + 1572864;          // 65536
  float* h1      = h0 + 65536;                 // 65536
  float* q_part  = h1 + 65536;                 // 8*65536 = 524288
  float* scoresp = q_part + 524288;            // 131072
  float* part    = scoresp + 131072;           // 64*32*1028 = 2105344
  float* pl      = part + 2105344;             // 64*50257 = 3216448
  float2* plsm   = (float2*)(pl + 3216448);    // 64*3144 float2 = 402432 floats
  unsigned short* catb = (unsigned short*)((float*)plsm + 402432);  // 64*2048 bf16

  float* out0 = (float*)d_out;                       // [B, V]
  float* out1 = out0 + (size_t)Bdim * Vdim;          // [2, B, H]
  float* out2 = out1 + (size_t)2 * Bdim * Hdim;      // [B, H]
  float* out3 = out2 + (size_t)Bdim * Hdim;          // [B, T]

  // 1-2: GRU layer 0 (kLen=128: 16 gi splits + 8 gh splits)
  k_gru_gemm<true><<<dim3(48, 24), 256, 0, stream>>>(
      inputs, E, context, hidden, W_ih0, W_hh0, gi_part, gh_part, 16, 128);
  k_gate<<<256, 256, 0, stream>>>(gi_part, 16, gh_part, 8, b_ih0, b_hh0, hidden,
                                  inputs, E, h0, out1, nullptr);

  // 3-4: GRU layer 1 (8 + 8 splits; gate also writes catb h1-half)
  k_gru_gemm<false><<<dim3(48, 16), 256, 0, stream>>>(
      inputs, h0, nullptr, hidden + Bdim * Hdim, W_ih1, W_hh1, gi_part, gh_part, 8, 128);
  k_gate<<<256, 256, 0, stream>>>(gi_part, 8, gh_part, 8, b_ih1, b_hh1,
                                  hidden + Bdim * Hdim, inputs, E, h1,
                                  out1 + Bdim * Hdim, catb);

  // 5: q = h1 @ Wa (split-K 8x128) -> q_part (summed inline by scores blocks)
  k_qgemm<<<dim3(16, 8), 256, 0, stream>>>(h1, Wa, q_part);

  // 6: Wo K-half1 ∥ scores+partial-ctx (pipelined, REP=1 — the r10 win)
  k_fused2<<<NWOB + NSB, 256, 0, stream>>>(enc, q_part, scoresp, part, catb, Wo, pl);

  // 7: combine -> context, catb ctx-half, attn output
  k_ctx_combine<<<64, 256, 0, stream>>>(part, scoresp, out2, catb, out3);

  // 8: Wo K-half2 + bias + tanh + lsm partials — REPW=5 instrumented
  k_wo2<<<NWOB, 256, 0, stream>>>(catb, Wo, bo, pl, out0, plsm);

  // 9: log_softmax finalize
  k_lsm_final<<<dim3(64, 4), 256, 0, stream>>>(out0, plsm);
}

// Round 13
// 371.116 us; speedup vs baseline: 2.1198x; 2.1198x over previous
//
#include <hip/hip_runtime.h>
#include <hip/hip_bf16.h>
#include <math.h>

#define Hdim 1024
#define Vdim 50257
#define Bdim 64
#define Tdim 2048

#define TCH 64
#define NCHUNK (Tdim / TCH)  // 32
#define PSTRIDE (Hdim + 4)
#define NWOB 786             // ceil(50257/64) Wo blocks (64 cols each)
#define NSB 2048             // scores blocks (64 batch x 32 chunks)
#define PLS 3144             // lsm partials per row = NWOB*4 waves

typedef short bf16x8 __attribute__((ext_vector_type(8)));
typedef float f32x4 __attribute__((ext_vector_type(4)));

__device__ __forceinline__ unsigned short f2bf(float f) {
  unsigned int u = __float_as_uint(f);
  unsigned int r = u + 0x7FFFu + ((u >> 16) & 1u);  // RNE
  return (unsigned short)(r >> 16);
}

// guarded online-softmax merge: never produces NaN when either side empty
__device__ __forceinline__ void mlmerge(float& m, float& l, float mo, float lo) {
  float M = fmaxf(m, mo);
  float a = (l == 0.f) ? 0.f : l * __expf(m - M);
  float c = (lo == 0.f) ? 0.f : lo * __expf(mo - M);
  m = M;
  l = a + c;
}

// ---------------- fused GRU GEMM (both ih and hh jobs in one launch) --------
template <bool FUSED>
__global__ __launch_bounds__(256) void k_gru_gemm(
    const int* __restrict__ idx, const float* __restrict__ Ai,
    const float* __restrict__ ctx, const float* __restrict__ Ah,
    const float* __restrict__ Wi, const float* __restrict__ Wh,
    float* __restrict__ gi_part, float* __restrict__ gh_part, int nSplitI,
    int kLen) {
  __shared__ float As[16][68];
  __shared__ float Ws[16][68];
  int tid = threadIdx.x;
  bool isI = (int)blockIdx.y < nSplitI;
  int split = isI ? blockIdx.y : (blockIdx.y - nSplitI);
  const float* W = isI ? Wi : Wh;
  int ldw = (FUSED && isI) ? 2048 : 1024;
  int kBase = split * kLen;
  int nIter = kLen >> 4;
  int tx = tid & 15, ty = tid >> 4;
  int n0 = blockIdx.x * 64;

  int am = tid >> 2, akk = (tid & 3) << 2;
  int wn = tid >> 2, wkk = (tid & 3) << 2;

  float acc[4][4];
#pragma unroll
  for (int i = 0; i < 4; i++)
#pragma unroll
    for (int j = 0; j < 4; j++) acc[i][j] = 0.f;

  float4 aReg, wReg;
  auto loadTile = [&](int k0) {
    int kg = k0 + akk;
    const float* asrc;
    if (isI) {
      if (FUSED)
        asrc = (kg < 1024) ? (Ai + (long)idx[am] * 1024 + kg)
                           : (ctx + (long)am * 1024 + (kg - 1024));
      else
        asrc = Ai + (long)am * 1024 + kg;
    } else {
      asrc = Ah + (long)am * 1024 + kg;
    }
    aReg = *(const float4*)asrc;
    wReg = *(const float4*)(W + (long)(n0 + wn) * ldw + k0 + wkk);
  };

  loadTile(kBase);
  for (int it = 0; it < nIter; ++it) {
    if (it) __syncthreads();
    As[akk + 0][am] = aReg.x; As[akk + 1][am] = aReg.y;
    As[akk + 2][am] = aReg.z; As[akk + 3][am] = aReg.w;
    Ws[wkk + 0][wn] = wReg.x; Ws[wkk + 1][wn] = wReg.y;
    Ws[wkk + 2][wn] = wReg.z; Ws[wkk + 3][wn] = wReg.w;
    __syncthreads();
    if (it + 1 < nIter) loadTile(kBase + (it + 1) * 16);
#pragma unroll
    for (int k = 0; k < 16; ++k) {
      float4 a = *(const float4*)&As[k][ty << 2];
      float4 w = *(const float4*)&Ws[k][tx << 2];
      acc[0][0] += a.x * w.x; acc[0][1] += a.x * w.y; acc[0][2] += a.x * w.z; acc[0][3] += a.x * w.w;
      acc[1][0] += a.y * w.x; acc[1][1] += a.y * w.y; acc[1][2] += a.y * w.z; acc[1][3] += a.y * w.w;
      acc[2][0] += a.z * w.x; acc[2][1] += a.z * w.y; acc[2][2] += a.z * w.z; acc[2][3] += a.z * w.w;
      acc[3][0] += a.w * w.x; acc[3][1] += a.w * w.y; acc[3][2] += a.w * w.z; acc[3][3] += a.w * w.w;
    }
  }
  float* C = (isI ? gi_part : gh_part) + (long)split * 64 * 3072;
#pragma unroll
  for (int i = 0; i < 4; i++) {
    int m = (ty << 2) + i;
#pragma unroll
    for (int j = 0; j < 4; j++) {
      int n = n0 + (tx << 2) + j;
      C[(long)m * 3072 + n] = acc[i][j];
    }
  }
}

// ---------------- GRU gate + split-K combine + fused outputs ----------------
__global__ void k_gate(const float* __restrict__ gi_part, int ski,
                       const float* __restrict__ gh_part, int skh,
                       const float* __restrict__ b_ih, const float* __restrict__ b_hh,
                       const float* __restrict__ hprev,
                       const int* __restrict__ idx, const float* __restrict__ E,
                       float* __restrict__ hout, float* __restrict__ out1_layer,
                       unsigned short* __restrict__ catb) {
  int i = blockIdx.x * blockDim.x + threadIdx.x;
  if (i >= Bdim * Hdim) return;
  int b = i >> 10, h = i & 1023;
  float ir = b_ih[h], iz = b_ih[Hdim + h], in = b_ih[2 * Hdim + h];
  float hr = b_hh[h], hz = b_hh[Hdim + h], hn = b_hh[2 * Hdim + h];
  for (int s = 0; s < ski; ++s) {
    const float* g = gi_part + ((long)s * 64 + b) * 3072;
    ir += g[h]; iz += g[Hdim + h]; in += g[2 * Hdim + h];
  }
  for (int s = 0; s < skh; ++s) {
    const float* g = gh_part + ((long)s * 64 + b) * 3072;
    hr += g[h]; hz += g[Hdim + h]; hn += g[2 * Hdim + h];
  }
  float r = 1.f / (1.f + __expf(-(ir + hr)));
  float z = 1.f / (1.f + __expf(-(iz + hz)));
  float n = tanhf(in + r * hn);
  float hv = (1.f - z) * n + z * hprev[i];
  hout[i] = hv;
  out1_layer[i] = hv + E[(long)idx[b] * 1024 + h];
  if (catb) catb[(long)b * 2048 + h] = f2bf(hv);
}

// ---------------- q = h1 @ Wa (TRANSW), split-K 8x128, reg-prefetch ---------
__global__ __launch_bounds__(256) void k_qgemm(const float* __restrict__ A,
                                               const float* __restrict__ W,
                                               float* __restrict__ Cpart) {
  __shared__ float As[16][68];
  __shared__ float Ws[16][68];
  int tid = threadIdx.x;
  int tx = tid & 15, ty = tid >> 4;
  int n0 = blockIdx.x * 64;
  int kBase = blockIdx.y * 128;
  int am = tid >> 2, akk = (tid & 3) << 2;
  int wkk = tid >> 4, wn4 = (tid & 15) << 2;

  float acc[4][4];
#pragma unroll
  for (int i = 0; i < 4; i++)
#pragma unroll
    for (int j = 0; j < 4; j++) acc[i][j] = 0.f;

  float4 aReg, wReg;
  auto loadTile = [&](int k0) {
    aReg = *(const float4*)(A + (long)am * 1024 + k0 + akk);
    wReg = *(const float4*)(W + (long)(k0 + wkk) * 1024 + n0 + wn4);
  };

  loadTile(kBase);
  for (int it = 0; it < 8; ++it) {
    if (it) __syncthreads();
    As[akk + 0][am] = aReg.x; As[akk + 1][am] = aReg.y;
    As[akk + 2][am] = aReg.z; As[akk + 3][am] = aReg.w;
    *(float4*)&Ws[wkk][wn4] = wReg;
    __syncthreads();
    if (it + 1 < 8) loadTile(kBase + (it + 1) * 16);
#pragma unroll
    for (int k = 0; k < 16; ++k) {
      float4 a = *(const float4*)&As[k][ty << 2];
      float4 w = *(const float4*)&Ws[k][tx << 2];
      acc[0][0] += a.x * w.x; acc[0][1] += a.x * w.y; acc[0][2] += a.x * w.z; acc[0][3] += a.x * w.w;
      acc[1][0] += a.y * w.x; acc[1][1] += a.y * w.y; acc[1][2] += a.y * w.z; acc[1][3] += a.y * w.w;
      acc[2][0] += a.z * w.x; acc[2][1] += a.z * w.y; acc[2][2] += a.z * w.z; acc[2][3] += a.z * w.w;
      acc[3][0] += a.w * w.x; acc[3][1] += a.w * w.y; acc[3][2] += a.w * w.z; acc[3][3] += a.w * w.w;
    }
  }
  float* C = Cpart + (long)blockIdx.y * 65536;
#pragma unroll
  for (int i = 0; i < 4; i++) {
    int m = (ty << 2) + i;
#pragma unroll
    for (int j = 0; j < 4; j++) {
      int n = n0 + (tx << 2) + j;
      C[(long)m * 1024 + n] = acc[i][j];
    }
  }
}

// ---------------- scores + online-softmax partial ctx (r10-pipelined) -------
__global__ __launch_bounds__(256) void k_scores(
    const float* __restrict__ enc, const float* __restrict__ q_part,
    float* __restrict__ scores, float* __restrict__ part) {
  __shared__ float s_acc[4][Hdim];
  __shared__ float s_ml[4][2];
  int tid = threadIdx.x, w = tid >> 6, lane = tid & 63;
  int b = blockIdx.x >> 5, ch = blockIdx.x & 31;
  auto qsum = [&](int p) {
    float4 r = make_float4(0.f, 0.f, 0.f, 0.f);
#pragma unroll
    for (int s = 0; s < 8; ++s) {
      float4 v = *(const float4*)(q_part + (long)s * 65536 + b * 1024 + p * 4);
      r.x += v.x; r.y += v.y; r.z += v.z; r.w += v.w;
    }
    return r;
  };
  float4 q0 = qsum(lane), q1 = qsum(lane + 64), q2 = qsum(lane + 128), q3 = qsum(lane + 192);
  int tbase = ch * TCH + w * 16;

  float m = -INFINITY, l = 0.f;
  float4 a0 = make_float4(0, 0, 0, 0), a1 = a0, a2 = a0, a3 = a0;
  const float4* e4 = (const float4*)(enc + ((long)tbase * Bdim + b) * Hdim);
  const float4* f4 = (const float4*)(enc + ((long)(tbase + 1) * Bdim + b) * Hdim);
  float4 eA0 = e4[lane], eA1 = e4[lane + 64], eA2 = e4[lane + 128], eA3 = e4[lane + 192];
  float4 fA0 = f4[lane], fA1 = f4[lane + 64], fA2 = f4[lane + 128], fA3 = f4[lane + 192];
#pragma unroll
  for (int i = 0; i < 16; i += 2) {
    float4 eB0, eB1, eB2, eB3, fB0, fB1, fB2, fB3;
    if (i + 2 < 16) {
      const float4* g4 = (const float4*)(enc + ((long)(tbase + i + 2) * Bdim + b) * Hdim);
      const float4* h4 = (const float4*)(enc + ((long)(tbase + i + 3) * Bdim + b) * Hdim);
      eB0 = g4[lane]; eB1 = g4[lane + 64]; eB2 = g4[lane + 128]; eB3 = g4[lane + 192];
      fB0 = h4[lane]; fB1 = h4[lane + 64]; fB2 = h4[lane + 128]; fB3 = h4[lane + 192];
    }
    float p = q0.x * eA0.x + q0.y * eA0.y + q0.z * eA0.z + q0.w * eA0.w
            + q1.x * eA1.x + q1.y * eA1.y + q1.z * eA1.z + q1.w * eA1.w
            + q2.x * eA2.x + q2.y * eA2.y + q2.z * eA2.z + q2.w * eA2.w
            + q3.x * eA3.x + q3.y * eA3.y + q3.z * eA3.z + q3.w * eA3.w;
    float p2 = q0.x * fA0.x + q0.y * fA0.y + q0.z * fA0.z + q0.w * fA0.w
             + q1.x * fA1.x + q1.y * fA1.y + q1.z * fA1.z + q1.w * fA1.w
             + q2.x * fA2.x + q2.y * fA2.y + q2.z * fA2.z + q2.w * fA2.w
             + q3.x * fA3.x + q3.y * fA3.y + q3.z * fA3.z + q3.w * fA3.w;
#pragma unroll
    for (int off = 1; off < 64; off <<= 1) {
      p += __shfl_xor(p, off, 64);
      p2 += __shfl_xor(p2, off, 64);
    }
    if (lane == 0) {
      scores[(long)b * Tdim + tbase + i] = p;
      scores[(long)b * Tdim + tbase + i + 1] = p2;
    }
    // defer-max: rescale only when the pair-max beats m by >8 (wave-uniform)
    float pm = fmaxf(p, p2);
    if (pm > m + 8.f) {
      float sc = __expf(m - pm);  // exp(-inf)=0 on first pair
      l *= sc;
      a0.x *= sc; a0.y *= sc; a0.z *= sc; a0.w *= sc;
      a1.x *= sc; a1.y *= sc; a1.z *= sc; a1.w *= sc;
      a2.x *= sc; a2.y *= sc; a2.z *= sc; a2.w *= sc;
      a3.x *= sc; a3.y *= sc; a3.z *= sc; a3.w *= sc;
      m = pm;
    }
    float w1 = __expf(p - m);   // bounded by e^8
    float w2 = __expf(p2 - m);
    l += w1 + w2;
    a0.x += w1 * eA0.x + w2 * fA0.x; a0.y += w1 * eA0.y + w2 * fA0.y;
    a0.z += w1 * eA0.z + w2 * fA0.z; a0.w += w1 * eA0.w + w2 * fA0.w;
    a1.x += w1 * eA1.x + w2 * fA1.x; a1.y += w1 * eA1.y + w2 * fA1.y;
    a1.z += w1 * eA1.z + w2 * fA1.z; a1.w += w1 * eA1.w + w2 * fA1.w;
    a2.x += w1 * eA2.x + w2 * fA2.x; a2.y += w1 * eA2.y + w2 * fA2.y;
    a2.z += w1 * eA2.z + w2 * fA2.z; a2.w += w1 * eA2.w + w2 * fA2.w;
    a3.x += w1 * eA3.x + w2 * fA3.x; a3.y += w1 * eA3.y + w2 * fA3.y;
    a3.z += w1 * eA3.z + w2 * fA3.z; a3.w += w1 * eA3.w + w2 * fA3.w;
    eA0 = eB0; eA1 = eB1; eA2 = eB2; eA3 = eB3;
    fA0 = fB0; fA1 = fB1; fA2 = fB2; fA3 = fB3;
  }
  float4* sa = (float4*)s_acc[w];
  sa[lane] = a0; sa[lane + 64] = a1; sa[lane + 128] = a2; sa[lane + 192] = a3;
  if (lane == 0) { s_ml[w][0] = m; s_ml[w][1] = l; }
  __syncthreads();
  float M = fmaxf(fmaxf(s_ml[0][0], s_ml[1][0]), fmaxf(s_ml[2][0], s_ml[3][0]));
  float L = 0.f;
  float4 o = make_float4(0, 0, 0, 0);
  for (int ww = 0; ww < 4; ++ww) {
    float wgt = __expf(s_ml[ww][0] - M);
    L += wgt * s_ml[ww][1];
    float4 v = ((const float4*)s_acc[ww])[tid];
    o.x += wgt * v.x; o.y += wgt * v.y; o.z += wgt * v.z; o.w += wgt * v.w;
  }
  float* pp = part + ((long)b * NCHUNK + ch) * PSTRIDE;
  ((float4*)pp)[tid] = o;
  if (tid == 0) { pp[Hdim] = M; pp[Hdim + 1] = L; }
}

// ---------------- combine partials -> context + catb + attn output ----------
__global__ void k_ctx_combine(const float* __restrict__ part,
                              const float* __restrict__ scores,
                              float* __restrict__ ctx_out,
                              unsigned short* __restrict__ catb,
                              float* __restrict__ attn_out) {
  int b = blockIdx.x, tid = threadIdx.x;  // 256
  __shared__ float ms[NCHUNK], ls[NCHUNK];
  if (tid < NCHUNK) {
    const float* pp = part + ((long)b * NCHUNK + tid) * PSTRIDE;
    ms[tid] = pp[Hdim];
    ls[tid] = pp[Hdim + 1];
  }
  __syncthreads();
  float m = -INFINITY;
  for (int c = 0; c < NCHUNK; ++c) m = fmaxf(m, ms[c]);
  float l = 0.f;
  for (int c = 0; c < NCHUNK; ++c) l += __expf(ms[c] - m) * ls[c];
  float4 a = make_float4(0, 0, 0, 0);
  for (int c = 0; c < NCHUNK; ++c) {
    float w = __expf(ms[c] - m);
    float4 v = ((const float4*)(part + ((long)b * NCHUNK + c) * PSTRIDE))[tid];
    a.x += w * v.x; a.y += w * v.y; a.z += w * v.z; a.w += w * v.w;
  }
  float inv = 1.f / l;
  a.x *= inv; a.y *= inv; a.z *= inv; a.w *= inv;
  ((float4*)(ctx_out + (long)b * Hdim))[tid] = a;
  ushort4 ob;
  ob.x = f2bf(a.x); ob.y = f2bf(a.y); ob.z = f2bf(a.z); ob.w = f2bf(a.w);
  *(ushort4*)(catb + (long)b * 2 * Hdim + Hdim + tid * 4) = ob;
  const float* srow = scores + (long)b * Tdim;
  float* arow = attn_out + (long)b * Tdim;
  for (int t = tid; t < Tdim; t += 256) arow[t] = __expf(srow[t] - m) * inv;
}

// ---------------- Wo GEMM full-K, LDS-staged coalesced B, + lsm partials ----
// Per 128-K chunk: coalesced float4 rounds (32 lanes = 512 contiguous B),
// convert fp32->bf16 once, ds_write to padded LDS; MFMA reads frags from LDS.
__global__ __launch_bounds__(256) void k_wo(const unsigned short* __restrict__ catb,
                                            const float* __restrict__ Wo,
                                            const float* __restrict__ bo,
                                            float* __restrict__ out,
                                            float2* __restrict__ plsm) {
  __shared__ unsigned short B_s[64][136];  // 128 + 8 pad: 16B-aligned rows, <=2-way banks
  int tid = threadIdx.x, w = tid >> 6, lane = tid & 63;
  int wb = blockIdx.x;
  int n = wb * 64 + w * 16 + (lane & 15);
  bool valid = n < Vdim;
  int kb = (lane >> 4) * 8;
  int r16 = lane & 15;
  int rbase = (lane >> 4) * 4;
  int nloc = w * 16 + (lane & 15);
  const unsigned short* ar0 = catb + (long)(r16) * 2048 + kb;
  const unsigned short* ar1 = catb + (long)(16 + r16) * 2048 + kb;
  const unsigned short* ar2 = catb + (long)(32 + r16) * 2048 + kb;
  const unsigned short* ar3 = catb + (long)(48 + r16) * 2048 + kb;
  int srow = tid >> 5;         // base staging row (0..7), + j*8
  int sf4 = (tid & 31) << 2;   // float offset within row (x4)

  f32x4 acc0 = {0.f, 0.f, 0.f, 0.f}, acc1 = acc0, acc2 = acc0, acc3 = acc0;
  float4 sreg[8];
  auto stageLoad = [&](int kc) {
#pragma unroll
    for (int j = 0; j < 8; ++j) {
      long gn = (long)wb * 64 + j * 8 + srow;
      sreg[j] = (gn < Vdim) ? *(const float4*)(Wo + gn * 2048 + kc + sf4)
                            : make_float4(0.f, 0.f, 0.f, 0.f);
    }
  };

  stageLoad(0);
  for (int c = 0; c < 16; ++c) {
    if (c) __syncthreads();  // previous chunk's ds_reads done
#pragma unroll
    for (int j = 0; j < 8; ++j) {
      ushort4 o;
      o.x = f2bf(sreg[j].x); o.y = f2bf(sreg[j].y);
      o.z = f2bf(sreg[j].z); o.w = f2bf(sreg[j].w);
      *(ushort4*)&B_s[j * 8 + srow][sf4] = o;
    }
    __syncthreads();
    if (c + 1 < 16) stageLoad((c + 1) * 128);  // prefetch under compute
    int kc = c * 128;
#pragma unroll
    for (int ks = 0; ks < 4; ++ks) {
      int kg = kc + ks * 32;
      bf16x8 a0 = *(const bf16x8*)(ar0 + kg);
      bf16x8 a1 = *(const bf16x8*)(ar1 + kg);
      bf16x8 a2 = *(const bf16x8*)(ar2 + kg);
      bf16x8 a3 = *(const bf16x8*)(ar3 + kg);
      bf16x8 bf = *(const bf16x8*)&B_s[nloc][ks * 32 + kb];
      acc0 = __builtin_amdgcn_mfma_f32_16x16x32_bf16(a0, bf, acc0, 0, 0, 0);
      acc1 = __builtin_amdgcn_mfma_f32_16x16x32_bf16(a1, bf, acc1, 0, 0, 0);
      acc2 = __builtin_amdgcn_mfma_f32_16x16x32_bf16(a2, bf, acc2, 0, 0, 0);
      acc3 = __builtin_amdgcn_mfma_f32_16x16x32_bf16(a3, bf, acc3, 0, 0, 0);
    }
  }
  float bias = valid ? bo[n] : 0.f;
  int widx = wb * 4 + w;
#define LSMG(G, ACCG)                                                          \
  {                                                                            \
    _Pragma("unroll") for (int r = 0; r < 4; ++r) {                            \
      float tv = tanhf(ACCG[r] + bias);                                        \
      if (valid) out[(long)(G * 16 + rbase + r) * Vdim + n] = tv;              \
      float mm = valid ? tv : -INFINITY;                                       \
      float ll = valid ? 1.f : 0.f;                                            \
      _Pragma("unroll") for (int msk = 1; msk < 16; msk <<= 1) {               \
        float mo = __shfl_xor(mm, msk, 64);                                    \
        float lo = __shfl_xor(ll, msk, 64);                                    \
        mlmerge(mm, ll, mo, lo);                                               \
      }                                                                        \
      if ((lane & 15) == 0)                                                    \
        plsm[(long)(G * 16 + rbase + r) * PLS + widx] = make_float2(mm, ll);   \
    }                                                                          \
  }
  LSMG(0, acc0)
  LSMG(1, acc1)
  LSMG(2, acc2)
  LSMG(3, acc3)
#undef LSMG
}

// ---------------- final log_softmax: reduce plsm + subtract ----------------
__global__ __launch_bounds__(256) void k_lsm_final(float* __restrict__ out,
                                                   const float2* __restrict__ plsm) {
  int b = blockIdx.x, c = blockIdx.y;
  int tid = threadIdx.x, w = tid >> 6, lane = tid & 63;
  float m = -INFINITY, l = 0.f;
  for (int i = tid; i < PLS; i += 256) {
    float2 p = plsm[(long)b * PLS + i];
    mlmerge(m, l, p.x, p.y);
  }
#pragma unroll
  for (int msk = 1; msk < 64; msk <<= 1) {
    float mo = __shfl_xor(m, msk, 64);
    float lo = __shfl_xor(l, msk, 64);
    mlmerge(m, l, mo, lo);
  }
  __shared__ float sm[4], sl[4];
  if (lane == 0) { sm[w] = m; sl[w] = l; }
  __syncthreads();
  float M = -INFINITY, L = 0.f;
#pragma unroll
  for (int i = 0; i < 4; ++i) mlmerge(M, L, sm[i], sl[i]);
  float lg = M + logf(L);
  const int seg = (Vdim + 3) / 4;
  int v0 = c * seg, v1 = min(v0 + seg, Vdim);
  float* row = out + (long)b * Vdim;
  for (int v = v0 + tid; v < v1; v += 256) row[v] -= lg;
}

extern "C" void kernel_launch(void* const* d_in, const int* in_sizes, int n_in,
                              void* d_out, int out_size, void* d_ws, size_t ws_size,
                              hipStream_t stream) {
  const int* inputs   = (const int*)d_in[0];
  const float* hidden = (const float*)d_in[1];
  const float* context= (const float*)d_in[2];
  const float* enc    = (const float*)d_in[3];
  const float* E      = (const float*)d_in[4];
  const float* W_ih0  = (const float*)d_in[5];
  const float* W_hh0  = (const float*)d_in[6];
  const float* b_ih0  = (const float*)d_in[7];
  const float* b_hh0  = (const float*)d_in[8];
  const float* W_ih1  = (const float*)d_in[9];
  const float* W_hh1  = (const float*)d_in[10];
  const float* b_ih1  = (const float*)d_in[11];
  const float* b_hh1  = (const float*)d_in[12];
  const float* Wa     = (const float*)d_in[13];
  // d_in[14] = ba: dropped — constant per-row score shift is softmax-invariant
  const float* Wo     = (const float*)d_in[15];
  const float* bo     = (const float*)d_in[16];

  float* ws = (float*)d_ws;
  float* gi_part = ws;                         // 16*64*3072 = 3145728
  float* gh_part = gi_part + 3145728;          // 8*64*3072 = 1572864
  float* h0      = gh_part + 1572864;          // 65536
  float* h1      = h0 + 65536;                 // 65536
  float* q_part  = h1 + 65536;                 // 8*65536 = 524288
  float* scoresp = q_part + 524288;            // 131072
  float* part    = scoresp + 131072;           // 64*32*1028 = 2105344
  float2* plsm   = (float2*)(part + 2105344);  // 64*3144 float2 = 402432 floats
  unsigned short* catb = (unsigned short*)((float*)plsm + 402432);  // 64*2048 bf16

  float* out0 = (float*)d_out;                       // [B, V]
  float* out1 = out0 + (size_t)Bdim * Vdim;          // [2, B, H]
  float* out2 = out1 + (size_t)2 * Bdim * Hdim;      // [B, H]
  float* out3 = out2 + (size_t)Bdim * Hdim;          // [B, T]

  // 1-2: GRU layer 0 (kLen=128: 16 gi splits + 8 gh splits)
  k_gru_gemm<true><<<dim3(48, 24), 256, 0, stream>>>(
      inputs, E, context, hidden, W_ih0, W_hh0, gi_part, gh_part, 16, 128);
  k_gate<<<256, 256, 0, stream>>>(gi_part, 16, gh_part, 8, b_ih0, b_hh0, hidden,
                                  inputs, E, h0, out1, nullptr);

  // 3-4: GRU layer 1 (8 + 8 splits; gate also writes catb h1-half)
  k_gru_gemm<false><<<dim3(48, 16), 256, 0, stream>>>(
      inputs, h0, nullptr, hidden + Bdim * Hdim, W_ih1, W_hh1, gi_part, gh_part, 8, 128);
  k_gate<<<256, 256, 0, stream>>>(gi_part, 8, gh_part, 8, b_ih1, b_hh1,
                                  hidden + Bdim * Hdim, inputs, E, h1,
                                  out1 + Bdim * Hdim, catb);

  // 5: q = h1 @ Wa (split-K 8x128) -> q_part (summed inline by scores blocks)
  k_qgemm<<<dim3(16, 8), 256, 0, stream>>>(h1, Wa, q_part);

  // 6: scores + online-softmax partial context (pipelined)
  k_scores<<<NSB, 256, 0, stream>>>(enc, q_part, scoresp, part);

  // 7: combine -> context, catb ctx-half, attn output
  k_ctx_combine<<<64, 256, 0, stream>>>(part, scoresp, out2, catb, out3);

  // 8: logits = tanh(catb @ Wo.T + bo), LDS-staged coalesced Wo, + lsm partials
  k_wo<<<NWOB, 256, 0, stream>>>(catb, Wo, bo, out0, plsm);

  // 9: log_softmax finalize
  k_lsm_final<<<dim3(64, 4), 256, 0, stream>>>(out0, plsm);
}

// Round 14
// 366.485 us; speedup vs baseline: 2.1466x; 1.0126x over previous
//
#include <hip/hip_runtime.h>
#include <hip/hip_bf16.h>
#include <math.h>

#define Hdim 1024
#define Vdim 50257
#define Bdim 64
#define Tdim 2048

#define TCH 64
#define NCHUNK (Tdim / TCH)  // 32
#define PSTRIDE (Hdim + 4)
#define NWOB 786             // wo-half1 blocks (64 cols each)
#define NSB 2048             // scores blocks
#define NWOB2 1571           // wo-half2 blocks (32 cols each)
#define PLS 3142             // lsm partials per row = NWOB2*2 waves

typedef short bf16x8 __attribute__((ext_vector_type(8)));
typedef float f32x4 __attribute__((ext_vector_type(4)));

__device__ __forceinline__ unsigned short f2bf(float f) {
  unsigned int u = __float_as_uint(f);
  unsigned int r = u + 0x7FFFu + ((u >> 16) & 1u);  // RNE
  return (unsigned short)(r >> 16);
}

// guarded online-softmax merge: never produces NaN when either side empty
__device__ __forceinline__ void mlmerge(float& m, float& l, float mo, float lo) {
  float M = fmaxf(m, mo);
  float a = (l == 0.f) ? 0.f : l * __expf(m - M);
  float c = (lo == 0.f) ? 0.f : lo * __expf(mo - M);
  m = M;
  l = a + c;
}

// ---------------- fused GRU GEMM (both ih and hh jobs in one launch) --------
template <bool FUSED>
__global__ __launch_bounds__(256) void k_gru_gemm(
    const int* __restrict__ idx, const float* __restrict__ Ai,
    const float* __restrict__ ctx, const float* __restrict__ Ah,
    const float* __restrict__ Wi, const float* __restrict__ Wh,
    float* __restrict__ gi_part, float* __restrict__ gh_part, int nSplitI,
    int kLen) {
  __shared__ float As[16][68];
  __shared__ float Ws[16][68];
  int tid = threadIdx.x;
  bool isI = (int)blockIdx.y < nSplitI;
  int split = isI ? blockIdx.y : (blockIdx.y - nSplitI);
  const float* W = isI ? Wi : Wh;
  int ldw = (FUSED && isI) ? 2048 : 1024;
  int kBase = split * kLen;
  int nIter = kLen >> 4;
  int tx = tid & 15, ty = tid >> 4;
  int n0 = blockIdx.x * 64;

  int am = tid >> 2, akk = (tid & 3) << 2;
  int wn = tid >> 2, wkk = (tid & 3) << 2;

  float acc[4][4];
#pragma unroll
  for (int i = 0; i < 4; i++)
#pragma unroll
    for (int j = 0; j < 4; j++) acc[i][j] = 0.f;

  float4 aReg, wReg;
  auto loadTile = [&](int k0) {
    int kg = k0 + akk;
    const float* asrc;
    if (isI) {
      if (FUSED)
        asrc = (kg < 1024) ? (Ai + (long)idx[am] * 1024 + kg)
                           : (ctx + (long)am * 1024 + (kg - 1024));
      else
        asrc = Ai + (long)am * 1024 + kg;
    } else {
      asrc = Ah + (long)am * 1024 + kg;
    }
    aReg = *(const float4*)asrc;
    wReg = *(const float4*)(W + (long)(n0 + wn) * ldw + k0 + wkk);
  };

  loadTile(kBase);
  for (int it = 0; it < nIter; ++it) {
    if (it) __syncthreads();
    As[akk + 0][am] = aReg.x; As[akk + 1][am] = aReg.y;
    As[akk + 2][am] = aReg.z; As[akk + 3][am] = aReg.w;
    Ws[wkk + 0][wn] = wReg.x; Ws[wkk + 1][wn] = wReg.y;
    Ws[wkk + 2][wn] = wReg.z; Ws[wkk + 3][wn] = wReg.w;
    __syncthreads();
    if (it + 1 < nIter) loadTile(kBase + (it + 1) * 16);
#pragma unroll
    for (int k = 0; k < 16; ++k) {
      float4 a = *(const float4*)&As[k][ty << 2];
      float4 w = *(const float4*)&Ws[k][tx << 2];
      acc[0][0] += a.x * w.x; acc[0][1] += a.x * w.y; acc[0][2] += a.x * w.z; acc[0][3] += a.x * w.w;
      acc[1][0] += a.y * w.x; acc[1][1] += a.y * w.y; acc[1][2] += a.y * w.z; acc[1][3] += a.y * w.w;
      acc[2][0] += a.z * w.x; acc[2][1] += a.z * w.y; acc[2][2] += a.z * w.z; acc[2][3] += a.z * w.w;
      acc[3][0] += a.w * w.x; acc[3][1] += a.w * w.y; acc[3][2] += a.w * w.z; acc[3][3] += a.w * w.w;
    }
  }
  float* C = (isI ? gi_part : gh_part) + (long)split * 64 * 3072;
#pragma unroll
  for (int i = 0; i < 4; i++) {
    int m = (ty << 2) + i;
#pragma unroll
    for (int j = 0; j < 4; j++) {
      int n = n0 + (tx << 2) + j;
      C[(long)m * 3072 + n] = acc[i][j];
    }
  }
}

// ---------------- GRU gate + split-K combine + fused outputs ----------------
__global__ void k_gate(const float* __restrict__ gi_part, int ski,
                       const float* __restrict__ gh_part, int skh,
                       const float* __restrict__ b_ih, const float* __restrict__ b_hh,
                       const float* __restrict__ hprev,
                       const int* __restrict__ idx, const float* __restrict__ E,
                       float* __restrict__ hout, float* __restrict__ out1_layer,
                       unsigned short* __restrict__ catb) {
  int i = blockIdx.x * blockDim.x + threadIdx.x;
  if (i >= Bdim * Hdim) return;
  int b = i >> 10, h = i & 1023;
  float ir = b_ih[h], iz = b_ih[Hdim + h], in = b_ih[2 * Hdim + h];
  float hr = b_hh[h], hz = b_hh[Hdim + h], hn = b_hh[2 * Hdim + h];
  for (int s = 0; s < ski; ++s) {
    const float* g = gi_part + ((long)s * 64 + b) * 3072;
    ir += g[h]; iz += g[Hdim + h]; in += g[2 * Hdim + h];
  }
  for (int s = 0; s < skh; ++s) {
    const float* g = gh_part + ((long)s * 64 + b) * 3072;
    hr += g[h]; hz += g[Hdim + h]; hn += g[2 * Hdim + h];
  }
  float r = 1.f / (1.f + __expf(-(ir + hr)));
  float z = 1.f / (1.f + __expf(-(iz + hz)));
  float n = tanhf(in + r * hn);
  float hv = (1.f - z) * n + z * hprev[i];
  hout[i] = hv;
  out1_layer[i] = hv + E[(long)idx[b] * 1024 + h];
  if (catb) catb[(long)b * 2048 + h] = f2bf(hv);
}

// ---------------- q = h1 @ Wa (TRANSW), split-K 8x128, reg-prefetch ---------
__global__ __launch_bounds__(256) void k_qgemm(const float* __restrict__ A,
                                               const float* __restrict__ W,
                                               float* __restrict__ Cpart) {
  __shared__ float As[16][68];
  __shared__ float Ws[16][68];
  int tid = threadIdx.x;
  int tx = tid & 15, ty = tid >> 4;
  int n0 = blockIdx.x * 64;
  int kBase = blockIdx.y * 128;
  int am = tid >> 2, akk = (tid & 3) << 2;
  int wkk = tid >> 4, wn4 = (tid & 15) << 2;

  float acc[4][4];
#pragma unroll
  for (int i = 0; i < 4; i++)
#pragma unroll
    for (int j = 0; j < 4; j++) acc[i][j] = 0.f;

  float4 aReg, wReg;
  auto loadTile = [&](int k0) {
    aReg = *(const float4*)(A + (long)am * 1024 + k0 + akk);
    wReg = *(const float4*)(W + (long)(k0 + wkk) * 1024 + n0 + wn4);
  };

  loadTile(kBase);
  for (int it = 0; it < 8; ++it) {
    if (it) __syncthreads();
    As[akk + 0][am] = aReg.x; As[akk + 1][am] = aReg.y;
    As[akk + 2][am] = aReg.z; As[akk + 3][am] = aReg.w;
    *(float4*)&Ws[wkk][wn4] = wReg;
    __syncthreads();
    if (it + 1 < 8) loadTile(kBase + (it + 1) * 16);
#pragma unroll
    for (int k = 0; k < 16; ++k) {
      float4 a = *(const float4*)&As[k][ty << 2];
      float4 w = *(const float4*)&Ws[k][tx << 2];
      acc[0][0] += a.x * w.x; acc[0][1] += a.x * w.y; acc[0][2] += a.x * w.z; acc[0][3] += a.x * w.w;
      acc[1][0] += a.y * w.x; acc[1][1] += a.y * w.y; acc[1][2] += a.y * w.z; acc[1][3] += a.y * w.w;
      acc[2][0] += a.z * w.x; acc[2][1] += a.z * w.y; acc[2][2] += a.z * w.z; acc[2][3] += a.z * w.w;
      acc[3][0] += a.w * w.x; acc[3][1] += a.w * w.y; acc[3][2] += a.w * w.z; acc[3][3] += a.w * w.w;
    }
  }
  float* C = Cpart + (long)blockIdx.y * 65536;
#pragma unroll
  for (int i = 0; i < 4; i++) {
    int m = (ty << 2) + i;
#pragma unroll
    for (int j = 0; j < 4; j++) {
      int n = n0 + (tx << 2) + j;
      C[(long)m * 1024 + n] = acc[i][j];
    }
  }
}

// ---------------- fused: wo-half1 staged (blocks [0,NWOB)) ∥ scores ---------
__global__ __launch_bounds__(256) void k_fused(
    const float* __restrict__ enc, const float* __restrict__ q_part,
    float* __restrict__ scores, float* __restrict__ part,
    const unsigned short* __restrict__ catb, const float* __restrict__ Wo,
    float* __restrict__ pl) {
  __shared__ __align__(16) char smem[17408];  // union: B_s[64][136] / s_acc[4][1024]
  __shared__ float s_ml[4][2];
  int tid = threadIdx.x, w = tid >> 6, lane = tid & 63;

  if (blockIdx.x < NWOB) {
    // ------ Wo GEMM K in [0,1024), LDS-staged coalesced, partial logits -----
    unsigned short (*B_s)[136] = (unsigned short(*)[136])smem;
    int wb = blockIdx.x;
    int n = wb * 64 + w * 16 + (lane & 15);
    bool valid = n < Vdim;
    int kb = (lane >> 4) * 8;
    int r16 = lane & 15;
    int nloc = w * 16 + (lane & 15);
    const unsigned short* ar0 = catb + (long)(r16) * 2048 + kb;
    const unsigned short* ar1 = catb + (long)(16 + r16) * 2048 + kb;
    const unsigned short* ar2 = catb + (long)(32 + r16) * 2048 + kb;
    const unsigned short* ar3 = catb + (long)(48 + r16) * 2048 + kb;
    int srow = tid >> 5;
    int sf4 = (tid & 31) << 2;
    f32x4 acc0 = {0.f, 0.f, 0.f, 0.f}, acc1 = acc0, acc2 = acc0, acc3 = acc0;
    float4 sreg[8];
    auto stageLoad = [&](int kc) {
#pragma unroll
      for (int j = 0; j < 8; ++j) {
        long gn = (long)wb * 64 + j * 8 + srow;
        sreg[j] = (gn < Vdim) ? *(const float4*)(Wo + gn * 2048 + kc + sf4)
                              : make_float4(0.f, 0.f, 0.f, 0.f);
      }
    };
    stageLoad(0);
    for (int c = 0; c < 8; ++c) {
      if (c) __syncthreads();
#pragma unroll
      for (int j = 0; j < 8; ++j) {
        ushort4 o;
        o.x = f2bf(sreg[j].x); o.y = f2bf(sreg[j].y);
        o.z = f2bf(sreg[j].z); o.w = f2bf(sreg[j].w);
        *(ushort4*)&B_s[j * 8 + srow][sf4] = o;
      }
      __syncthreads();
      if (c + 1 < 8) stageLoad((c + 1) * 128);
      int kc = c * 128;
#pragma unroll
      for (int ks = 0; ks < 4; ++ks) {
        int kg = kc + ks * 32;
        bf16x8 a0 = *(const bf16x8*)(ar0 + kg);
        bf16x8 a1 = *(const bf16x8*)(ar1 + kg);
        bf16x8 a2 = *(const bf16x8*)(ar2 + kg);
        bf16x8 a3 = *(const bf16x8*)(ar3 + kg);
        bf16x8 bf = *(const bf16x8*)&B_s[nloc][ks * 32 + kb];
        acc0 = __builtin_amdgcn_mfma_f32_16x16x32_bf16(a0, bf, acc0, 0, 0, 0);
        acc1 = __builtin_amdgcn_mfma_f32_16x16x32_bf16(a1, bf, acc1, 0, 0, 0);
        acc2 = __builtin_amdgcn_mfma_f32_16x16x32_bf16(a2, bf, acc2, 0, 0, 0);
        acc3 = __builtin_amdgcn_mfma_f32_16x16x32_bf16(a3, bf, acc3, 0, 0, 0);
      }
    }
    if (valid) {
      int rbase = (lane >> 4) * 4;
#pragma unroll
      for (int r = 0; r < 4; ++r) {
        pl[(long)(0 * 16 + rbase + r) * Vdim + n] = acc0[r];
        pl[(long)(1 * 16 + rbase + r) * Vdim + n] = acc1[r];
        pl[(long)(2 * 16 + rbase + r) * Vdim + n] = acc2[r];
        pl[(long)(3 * 16 + rbase + r) * Vdim + n] = acc3[r];
      }
    }
    return;
  }

  // ---------- scores + online-softmax partial context (r10-pipelined) ------
  float (*s_acc)[Hdim] = (float(*)[Hdim])smem;
  int sb = blockIdx.x - NWOB;
  int b = sb >> 5, ch = sb & 31;
  auto qsum = [&](int p) {
    float4 r = make_float4(0.f, 0.f, 0.f, 0.f);
#pragma unroll
    for (int s = 0; s < 8; ++s) {
      float4 v = *(const float4*)(q_part + (long)s * 65536 + b * 1024 + p * 4);
      r.x += v.x; r.y += v.y; r.z += v.z; r.w += v.w;
    }
    return r;
  };
  float4 q0 = qsum(lane), q1 = qsum(lane + 64), q2 = qsum(lane + 128), q3 = qsum(lane + 192);
  int tbase = ch * TCH + w * 16;

  float m = -INFINITY, l = 0.f;
  float4 a0 = make_float4(0, 0, 0, 0), a1 = a0, a2 = a0, a3 = a0;
  const float4* e4 = (const float4*)(enc + ((long)tbase * Bdim + b) * Hdim);
  const float4* f4 = (const float4*)(enc + ((long)(tbase + 1) * Bdim + b) * Hdim);
  float4 eA0 = e4[lane], eA1 = e4[lane + 64], eA2 = e4[lane + 128], eA3 = e4[lane + 192];
  float4 fA0 = f4[lane], fA1 = f4[lane + 64], fA2 = f4[lane + 128], fA3 = f4[lane + 192];
#pragma unroll
  for (int i = 0; i < 16; i += 2) {
    float4 eB0, eB1, eB2, eB3, fB0, fB1, fB2, fB3;
    if (i + 2 < 16) {
      const float4* g4 = (const float4*)(enc + ((long)(tbase + i + 2) * Bdim + b) * Hdim);
      const float4* h4 = (const float4*)(enc + ((long)(tbase + i + 3) * Bdim + b) * Hdim);
      eB0 = g4[lane]; eB1 = g4[lane + 64]; eB2 = g4[lane + 128]; eB3 = g4[lane + 192];
      fB0 = h4[lane]; fB1 = h4[lane + 64]; fB2 = h4[lane + 128]; fB3 = h4[lane + 192];
    }
    float p = q0.x * eA0.x + q0.y * eA0.y + q0.z * eA0.z + q0.w * eA0.w
            + q1.x * eA1.x + q1.y * eA1.y + q1.z * eA1.z + q1.w * eA1.w
            + q2.x * eA2.x + q2.y * eA2.y + q2.z * eA2.z + q2.w * eA2.w
            + q3.x * eA3.x + q3.y * eA3.y + q3.z * eA3.z + q3.w * eA3.w;
    float p2 = q0.x * fA0.x + q0.y * fA0.y + q0.z * fA0.z + q0.w * fA0.w
             + q1.x * fA1.x + q1.y * fA1.y + q1.z * fA1.z + q1.w * fA1.w
             + q2.x * fA2.x + q2.y * fA2.y + q2.z * fA2.z + q2.w * fA2.w
             + q3.x * fA3.x + q3.y * fA3.y + q3.z * fA3.z + q3.w * fA3.w;
#pragma unroll
    for (int off = 1; off < 64; off <<= 1) {
      p += __shfl_xor(p, off, 64);
      p2 += __shfl_xor(p2, off, 64);
    }
    if (lane == 0) {
      scores[(long)b * Tdim + tbase + i] = p;
      scores[(long)b * Tdim + tbase + i + 1] = p2;
    }
    // defer-max: rescale only when the pair-max beats m by >8 (wave-uniform)
    float pm = fmaxf(p, p2);
    if (pm > m + 8.f) {
      float sc = __expf(m - pm);  // exp(-inf)=0 on first pair
      l *= sc;
      a0.x *= sc; a0.y *= sc; a0.z *= sc; a0.w *= sc;
      a1.x *= sc; a1.y *= sc; a1.z *= sc; a1.w *= sc;
      a2.x *= sc; a2.y *= sc; a2.z *= sc; a2.w *= sc;
      a3.x *= sc; a3.y *= sc; a3.z *= sc; a3.w *= sc;
      m = pm;
    }
    float w1 = __expf(p - m);   // bounded by e^8
    float w2 = __expf(p2 - m);
    l += w1 + w2;
    a0.x += w1 * eA0.x + w2 * fA0.x; a0.y += w1 * eA0.y + w2 * fA0.y;
    a0.z += w1 * eA0.z + w2 * fA0.z; a0.w += w1 * eA0.w + w2 * fA0.w;
    a1.x += w1 * eA1.x + w2 * fA1.x; a1.y += w1 * eA1.y + w2 * fA1.y;
    a1.z += w1 * eA1.z + w2 * fA1.z; a1.w += w1 * eA1.w + w2 * fA1.w;
    a2.x += w1 * eA2.x + w2 * fA2.x; a2.y += w1 * eA2.y + w2 * fA2.y;
    a2.z += w1 * eA2.z + w2 * fA2.z; a2.w += w1 * eA2.w + w2 * fA2.w;
    a3.x += w1 * eA3.x + w2 * fA3.x; a3.y += w1 * eA3.y + w2 * fA3.y;
    a3.z += w1 * eA3.z + w2 * fA3.z; a3.w += w1 * eA3.w + w2 * fA3.w;
    eA0 = eB0; eA1 = eB1; eA2 = eB2; eA3 = eB3;
    fA0 = fB0; fA1 = fB1; fA2 = fB2; fA3 = fB3;
  }
  float4* sa = (float4*)s_acc[w];
  sa[lane] = a0; sa[lane + 64] = a1; sa[lane + 128] = a2; sa[lane + 192] = a3;
  if (lane == 0) { s_ml[w][0] = m; s_ml[w][1] = l; }
  __syncthreads();
  float M = fmaxf(fmaxf(s_ml[0][0], s_ml[1][0]), fmaxf(s_ml[2][0], s_ml[3][0]));
  float L = 0.f;
  float4 o = make_float4(0, 0, 0, 0);
  for (int ww = 0; ww < 4; ++ww) {
    float wgt = __expf(s_ml[ww][0] - M);
    L += wgt * s_ml[ww][1];
    float4 v = ((const float4*)s_acc[ww])[tid];
    o.x += wgt * v.x; o.y += wgt * v.y; o.z += wgt * v.z; o.w += wgt * v.w;
  }
  float* pp = part + ((long)b * NCHUNK + ch) * PSTRIDE;
  ((float4*)pp)[tid] = o;
  if (tid == 0) { pp[Hdim] = M; pp[Hdim + 1] = L; }
}

// ---------------- combine partials -> context + catb + attn output ----------
__global__ void k_ctx_combine(const float* __restrict__ part,
                              const float* __restrict__ scores,
                              float* __restrict__ ctx_out,
                              unsigned short* __restrict__ catb,
                              float* __restrict__ attn_out) {
  int b = blockIdx.x, tid = threadIdx.x;  // 256
  __shared__ float ms[NCHUNK], ls[NCHUNK];
  if (tid < NCHUNK) {
    const float* pp = part + ((long)b * NCHUNK + tid) * PSTRIDE;
    ms[tid] = pp[Hdim];
    ls[tid] = pp[Hdim + 1];
  }
  __syncthreads();
  float m = -INFINITY;
  for (int c = 0; c < NCHUNK; ++c) m = fmaxf(m, ms[c]);
  float l = 0.f;
  for (int c = 0; c < NCHUNK; ++c) l += __expf(ms[c] - m) * ls[c];
  float4 a = make_float4(0, 0, 0, 0);
  for (int c = 0; c < NCHUNK; ++c) {
    float w = __expf(ms[c] - m);
    float4 v = ((const float4*)(part + ((long)b * NCHUNK + c) * PSTRIDE))[tid];
    a.x += w * v.x; a.y += w * v.y; a.z += w * v.z; a.w += w * v.w;
  }
  float inv = 1.f / l;
  a.x *= inv; a.y *= inv; a.z *= inv; a.w *= inv;
  ((float4*)(ctx_out + (long)b * Hdim))[tid] = a;
  ushort4 ob;
  ob.x = f2bf(a.x); ob.y = f2bf(a.y); ob.z = f2bf(a.z); ob.w = f2bf(a.w);
  *(ushort4*)(catb + (long)b * 2 * Hdim + Hdim + tid * 4) = ob;
  const float* srow = scores + (long)b * Tdim;
  float* arow = attn_out + (long)b * Tdim;
  for (int t = tid; t < Tdim; t += 256) arow[t] = __expf(srow[t] - m) * inv;
}

// ---------------- Wo half-2: 32-col blocks, LDS-staged, + lsm partials ------
__global__ __launch_bounds__(128) void k_wo2(const unsigned short* __restrict__ catb,
                                             const float* __restrict__ Wo,
                                             const float* __restrict__ bo,
                                             const float* __restrict__ pl,
                                             float* __restrict__ out,
                                             float2* __restrict__ plsm) {
  __shared__ unsigned short B_s[32][136];
  int tid = threadIdx.x, w = tid >> 6, lane = tid & 63;
  int wb = blockIdx.x;
  int n = wb * 32 + w * 16 + (lane & 15);
  bool valid = n < Vdim;
  int kb = (lane >> 4) * 8;
  int r16 = lane & 15;
  int rbase = (lane >> 4) * 4;
  int nloc = w * 16 + (lane & 15);
  const unsigned short* ar0 = catb + (long)(r16) * 2048 + kb;
  const unsigned short* ar1 = catb + (long)(16 + r16) * 2048 + kb;
  const unsigned short* ar2 = catb + (long)(32 + r16) * 2048 + kb;
  const unsigned short* ar3 = catb + (long)(48 + r16) * 2048 + kb;
  int srow = tid >> 4;         // 0..7
  int sc = tid & 15;           // float4 index within half-row

  f32x4 acc0 = {0.f, 0.f, 0.f, 0.f}, acc1 = acc0, acc2 = acc0, acc3 = acc0;
  if (valid) {
#pragma unroll
    for (int r = 0; r < 4; ++r) {
      acc0[r] = pl[(long)(0 * 16 + rbase + r) * Vdim + n];
      acc1[r] = pl[(long)(1 * 16 + rbase + r) * Vdim + n];
      acc2[r] = pl[(long)(2 * 16 + rbase + r) * Vdim + n];
      acc3[r] = pl[(long)(3 * 16 + rbase + r) * Vdim + n];
    }
  }
  float4 sreg[8];
  auto stageLoad = [&](int kc) {
#pragma unroll
    for (int j = 0; j < 8; ++j) {
      int row = (j & 3) * 8 + srow;
      int cf4 = (j >> 2) * 16 + sc;
      long gn = (long)wb * 32 + row;
      sreg[j] = (gn < Vdim) ? *(const float4*)(Wo + gn * 2048 + kc + cf4 * 4)
                            : make_float4(0.f, 0.f, 0.f, 0.f);
    }
  };
  stageLoad(1024);
  for (int c = 0; c < 8; ++c) {
    if (c) __syncthreads();
#pragma unroll
    for (int j = 0; j < 8; ++j) {
      int row = (j & 3) * 8 + srow;
      int cf4 = (j >> 2) * 16 + sc;
      ushort4 o;
      o.x = f2bf(sreg[j].x); o.y = f2bf(sreg[j].y);
      o.z = f2bf(sreg[j].z); o.w = f2bf(sreg[j].w);
      *(ushort4*)&B_s[row][cf4 << 2] = o;
    }
    __syncthreads();
    if (c + 1 < 8) stageLoad(1024 + (c + 1) * 128);
    int kc = 1024 + c * 128;
#pragma unroll
    for (int ks = 0; ks < 4; ++ks) {
      int kg = kc + ks * 32;
      bf16x8 a0 = *(const bf16x8*)(ar0 + kg);
      bf16x8 a1 = *(const bf16x8*)(ar1 + kg);
      bf16x8 a2 = *(const bf16x8*)(ar2 + kg);
      bf16x8 a3 = *(const bf16x8*)(ar3 + kg);
      bf16x8 bf = *(const bf16x8*)&B_s[nloc][ks * 32 + kb];
      acc0 = __builtin_amdgcn_mfma_f32_16x16x32_bf16(a0, bf, acc0, 0, 0, 0);
      acc1 = __builtin_amdgcn_mfma_f32_16x16x32_bf16(a1, bf, acc1, 0, 0, 0);
      acc2 = __builtin_amdgcn_mfma_f32_16x16x32_bf16(a2, bf, acc2, 0, 0, 0);
      acc3 = __builtin_amdgcn_mfma_f32_16x16x32_bf16(a3, bf, acc3, 0, 0, 0);
    }
  }
  float bias = valid ? bo[n] : 0.f;
  int widx = wb * 2 + w;
#define LSMG(G, ACCG)                                                          \
  {                                                                            \
    _Pragma("unroll") for (int r = 0; r < 4; ++r) {                            \
      float tv = tanhf(ACCG[r] + bias);                                        \
      if (valid) out[(long)(G * 16 + rbase + r) * Vdim + n] = tv;              \
      float mm = valid ? tv : -INFINITY;                                       \
      float ll = valid ? 1.f : 0.f;                                            \
      _Pragma("unroll") for (int msk = 1; msk < 16; msk <<= 1) {               \
        float mo = __shfl_xor(mm, msk, 64);                                    \
        float lo = __shfl_xor(ll, msk, 64);                                    \
        mlmerge(mm, ll, mo, lo);                                               \
      }                                                                        \
      if ((lane & 15) == 0)                                                    \
        plsm[(long)(G * 16 + rbase + r) * PLS + widx] = make_float2(mm, ll);   \
    }                                                                          \
  }
  LSMG(0, acc0)
  LSMG(1, acc1)
  LSMG(2, acc2)
  LSMG(3, acc3)
#undef LSMG
}

// ---------------- final log_softmax: reduce plsm + subtract ----------------
__global__ __launch_bounds__(256) void k_lsm_final(float* __restrict__ out,
                                                   const float2* __restrict__ plsm) {
  int b = blockIdx.x, c = blockIdx.y;
  int tid = threadIdx.x, w = tid >> 6, lane = tid & 63;
  float m = -INFINITY, l = 0.f;
  for (int i = tid; i < PLS; i += 256) {
    float2 p = plsm[(long)b * PLS + i];
    mlmerge(m, l, p.x, p.y);
  }
#pragma unroll
  for (int msk = 1; msk < 64; msk <<= 1) {
    float mo = __shfl_xor(m, msk, 64);
    float lo = __shfl_xor(l, msk, 64);
    mlmerge(m, l, mo, lo);
  }
  __shared__ float sm[4], sl[4];
  if (lane == 0) { sm[w] = m; sl[w] = l; }
  __syncthreads();
  float M = -INFINITY, L = 0.f;
#pragma unroll
  for (int i = 0; i < 4; ++i) mlmerge(M, L, sm[i], sl[i]);
  float lg = M + logf(L);
  const int seg = (Vdim + 3) / 4;
  int v0 = c * seg, v1 = min(v0 + seg, Vdim);
  float* row = out + (long)b * Vdim;
  for (int v = v0 + tid; v < v1; v += 256) row[v] -= lg;
}

extern "C" void kernel_launch(void* const* d_in, const int* in_sizes, int n_in,
                              void* d_out, int out_size, void* d_ws, size_t ws_size,
                              hipStream_t stream) {
  const int* inputs   = (const int*)d_in[0];
  const float* hidden = (const float*)d_in[1];
  const float* context= (const float*)d_in[2];
  const float* enc    = (const float*)d_in[3];
  const float* E      = (const float*)d_in[4];
  const float* W_ih0  = (const float*)d_in[5];
  const float* W_hh0  = (const float*)d_in[6];
  const float* b_ih0  = (const float*)d_in[7];
  const float* b_hh0  = (const float*)d_in[8];
  const float* W_ih1  = (const float*)d_in[9];
  const float* W_hh1  = (const float*)d_in[10];
  const float* b_ih1  = (const float*)d_in[11];
  const float* b_hh1  = (const float*)d_in[12];
  const float* Wa     = (const float*)d_in[13];
  // d_in[14] = ba: dropped — constant per-row score shift is softmax-invariant
  const float* Wo     = (const float*)d_in[15];
  const float* bo     = (const float*)d_in[16];

  float* ws = (float*)d_ws;
  float* gi_part = ws;                         // 16*64*3072 = 3145728
  float* gh_part = gi_part + 3145728;          // 8*64*3072 = 1572864
  float* h0      = gh_part + 1572864;          // 65536
  float* h1      = h0 + 65536;                 // 65536
  float* q_part  = h1 + 65536;                 // 8*65536 = 524288
  float* scoresp = q_part + 524288;            // 131072
  float* part    = scoresp + 131072;           // 64*32*1028 = 2105344
  float* pl      = part + 2105344;             // 64*50257 = 3216448
  float2* plsm   = (float2*)(pl + 3216448);    // 64*3142 float2 = 402176 floats
  unsigned short* catb = (unsigned short*)((float*)plsm + 402176);  // 64*2048 bf16

  float* out0 = (float*)d_out;                       // [B, V]
  float* out1 = out0 + (size_t)Bdim * Vdim;          // [2, B, H]
  float* out2 = out1 + (size_t)2 * Bdim * Hdim;      // [B, H]
  float* out3 = out2 + (size_t)Bdim * Hdim;          // [B, T]

  // 1-2: GRU layer 0 (kLen=128: 16 gi splits + 8 gh splits)
  k_gru_gemm<true><<<dim3(48, 24), 256, 0, stream>>>(
      inputs, E, context, hidden, W_ih0, W_hh0, gi_part, gh_part, 16, 128);
  k_gate<<<256, 256, 0, stream>>>(gi_part, 16, gh_part, 8, b_ih0, b_hh0, hidden,
                                  inputs, E, h0, out1, nullptr);

  // 3-4: GRU layer 1 (8 + 8 splits; gate also writes catb h1-half)
  k_gru_gemm<false><<<dim3(48, 16), 256, 0, stream>>>(
      inputs, h0, nullptr, hidden + Bdim * Hdim, W_ih1, W_hh1, gi_part, gh_part, 8, 128);
  k_gate<<<256, 256, 0, stream>>>(gi_part, 8, gh_part, 8, b_ih1, b_hh1,
                                  hidden + Bdim * Hdim, inputs, E, h1,
                                  out1 + Bdim * Hdim, catb);

  // 5: q = h1 @ Wa (split-K 8x128) -> q_part (summed inline by scores blocks)
  k_qgemm<<<dim3(16, 8), 256, 0, stream>>>(h1, Wa, q_part);

  // 6: wo-half1 staged (786) ∥ scores+partial-ctx (2048) — no inter-block sync
  k_fused<<<NWOB + NSB, 256, 0, stream>>>(enc, q_part, scoresp, part, catb, Wo, pl);

  // 7: combine -> context, catb ctx-half, attn output
  k_ctx_combine<<<64, 256, 0, stream>>>(part, scoresp, out2, catb, out3);

  // 8: wo-half2 staged, 32-col blocks (1571) + lsm partials
  k_wo2<<<NWOB2, 128, 0, stream>>>(catb, Wo, bo, pl, out0, plsm);

  // 9: log_softmax finalize
  k_lsm_final<<<dim3(64, 4), 256, 0, stream>>>(out0, plsm);
}